// Round 3
// baseline (163.321 us; speedup 1.0000x reference)
//
#include <hip/hip_runtime.h>
#include <math.h>

typedef __bf16 bf16x8 __attribute__((ext_vector_type(8)));
typedef float f32x4 __attribute__((ext_vector_type(4)));

#define MFMA16(a, b, c) __builtin_amdgcn_mfma_f32_16x16x32_bf16(a, b, c, 0, 0, 0)

static constexpr int M_TOT = 8192;   // B*S
static constexpr int DIN = 4096;
static constexpr int DOUT = 4096;
static constexpr int RNK = 64;

__device__ inline unsigned short f2bf(float f) {
    union { float f; unsigned u; } v; v.f = f;
    unsigned r = v.u + 0x7FFFu + ((v.u >> 16) & 1u);   // round-to-nearest-even
    return (unsigned short)(r >> 16);
}

// ---------------------------------------------------------------------------
// Prep: lora_A [64][4096] -> Abf (bf16) and Atbf (bf16, [4096][64])
//       lora_B [4096][64] -> Bbf (bf16)
// ---------------------------------------------------------------------------
__global__ __launch_bounds__(256) void k_prep(const float* __restrict__ A,
                                              const float* __restrict__ B,
                                              unsigned short* __restrict__ Abf,
                                              unsigned short* __restrict__ Atbf,
                                              unsigned short* __restrict__ Bbf) {
    int i = blockIdx.x * 256 + threadIdx.x;          // 0 .. 262143
    unsigned short ab = f2bf(A[i]);
    Abf[i] = ab;
    int r = i >> 12, c = i & 4095;                   // A is [64][4096]
    Atbf[c * RNK + r] = ab;
    Bbf[i] = f2bf(B[i]);
}

// ---------------------------------------------------------------------------
// K1: xa = x @ lora_A^T   [8192 x 64], bf16 output.
// Block = 512 threads (8 waves), 16-row M tile, K split 8 ways across waves.
// x is single-use -> non-temporal loads.
// ---------------------------------------------------------------------------
__global__ __launch_bounds__(512) void k1_xa(const float* __restrict__ x,
                                             const unsigned short* __restrict__ Abf,
                                             unsigned short* __restrict__ xabf) {
    __shared__ float red[8][1024];                   // 8 waves x (16m x 64r) = 32 KB
    int tid = threadIdx.x;
    int wid = tid >> 6, lane = tid & 63;
    int row = lane & 15, kq = lane >> 4;
    int m0 = blockIdx.x * 16;

    f32x4 acc0 = {0.f, 0.f, 0.f, 0.f};
    f32x4 acc1 = acc0, acc2 = acc0, acc3 = acc0;

    const float* xp = x + (size_t)(m0 + row) * DIN + wid * 512 + kq * 8;
    const unsigned short* ap = Abf + (size_t)row * DIN + wid * 512 + kq * 8;

    #pragma unroll 4
    for (int ks = 0; ks < 512; ks += 32) {
        f32x4 x0 = __builtin_nontemporal_load((const f32x4*)(xp + ks));
        f32x4 x1 = __builtin_nontemporal_load((const f32x4*)(xp + ks + 4));
        bf16x8 af;
        #pragma unroll
        for (int j = 0; j < 4; ++j) { af[j] = (__bf16)x0[j]; af[j + 4] = (__bf16)x1[j]; }
        acc0 = MFMA16(af, *(const bf16x8*)(ap + ks), acc0);
        acc1 = MFMA16(af, *(const bf16x8*)(ap + 16 * DIN + ks), acc1);
        acc2 = MFMA16(af, *(const bf16x8*)(ap + 32 * DIN + ks), acc2);
        acc3 = MFMA16(af, *(const bf16x8*)(ap + 48 * DIN + ks), acc3);
    }

    int mb = kq * 4;                                  // C: row = (lane>>4)*4 + reg
    #pragma unroll
    for (int rg = 0; rg < 4; ++rg) {
        red[wid][(mb + rg) * 64 + row]      = acc0[rg];
        red[wid][(mb + rg) * 64 + 16 + row] = acc1[rg];
        red[wid][(mb + rg) * 64 + 32 + row] = acc2[rg];
        red[wid][(mb + rg) * 64 + 48 + row] = acc3[rg];
    }
    __syncthreads();

    #pragma unroll
    for (int e = tid; e < 1024; e += 512) {
        float s = 0.f;
        #pragma unroll
        for (int w = 0; w < 8; ++w) s += red[w][e];
        xabf[(size_t)m0 * RNK + e] = f2bf(s);
    }
}

// ---------------------------------------------------------------------------
// K2: partial squared row-norms of (base_weight + 2*B@A).
// Grid = 256 o-tiles x 4 i-quarters; block (o,q) owns nrm2p[q*4096 + o0..o0+15].
// 4 independent accumulators (break the serial FMA chain); nt loads on bw.
// ---------------------------------------------------------------------------
__global__ __launch_bounds__(256) void k2_norm(const float* __restrict__ bw,
                                               const unsigned short* __restrict__ Bbf,
                                               const unsigned short* __restrict__ Atbf,
                                               float* __restrict__ nrm2p) {
    __shared__ float part[4][16];
    int tid = threadIdx.x;
    int wid = tid >> 6, lane = tid & 63;
    int row = lane & 15, kq = lane >> 4;
    int o0 = (blockIdx.x >> 2) * 16;
    int q  = blockIdx.x & 3;

    // B-operand: lora_B rows (o = lane&15), loop-invariant.
    bf16x8 b0 = *(const bf16x8*)(Bbf + (size_t)(o0 + row) * RNK + kq * 8);
    bf16x8 b1 = *(const bf16x8*)(Bbf + (size_t)(o0 + row) * RNK + 32 + kq * 8);

    f32x4 nacc = {0.f, 0.f, 0.f, 0.f};
    const float* bwp = bw + (size_t)(o0 + row) * DIN + q * 1024 + wid * 256 + kq * 4;
    const unsigned short* atp = Atbf + (size_t)(q * 1024 + wid * 256 + row) * RNK + kq * 8;

    #pragma unroll 4
    for (int ii = 0; ii < 16; ++ii) {
        bf16x8 a0 = *(const bf16x8*)(atp + (size_t)ii * 16 * RNK);
        bf16x8 a1 = *(const bf16x8*)(atp + (size_t)ii * 16 * RNK + 32);
        f32x4 d = {0.f, 0.f, 0.f, 0.f};
        d = MFMA16(a0, b0, d);                       // lane: delta[o=row][i = base + kq*4 + rg]
        d = MFMA16(a1, b1, d);
        f32x4 wv = __builtin_nontemporal_load((const f32x4*)(bwp + ii * 16));
        #pragma unroll
        for (int rg = 0; rg < 4; ++rg) {
            float w = wv[rg] + 2.0f * d[rg];
            nacc[rg] += w * w;
        }
    }
    float ns = nacc[0] + nacc[1] + nacc[2] + nacc[3];

    // reduce across the 4 kq groups (lanes row, row+16, row+32, row+48)
    ns += __shfl_xor(ns, 16, 64);
    ns += __shfl_xor(ns, 32, 64);
    if (kq == 0) part[wid][row] = ns;
    __syncthreads();
    if (tid < 16) {
        nrm2p[q * DOUT + o0 + tid] =
            part[0][tid] + part[1][tid] + part[2][tid] + part[3][tid];
    }
}

// ---------------------------------------------------------------------------
// K3: out = (base_output + 2 * xa @ lora_B^T) * mag/(sqrt(nrm2)+eps)
// Block = 256 threads (4 waves), tile 16m x 256n. Epilogue operands (base,
// nrm2p, mag) are loaded BEFORE the MFMA phase (issue-early / consume-late);
// mag_scale computed per-thread for its own 4 columns (k2b fused away).
// base/out single-use -> non-temporal.
// ---------------------------------------------------------------------------
__global__ __launch_bounds__(256) void k3_out(const float* __restrict__ base,
                                              const unsigned short* __restrict__ xabf,
                                              const unsigned short* __restrict__ Bbf,
                                              const float* __restrict__ nrm2p,
                                              const float* __restrict__ mag,
                                              float* __restrict__ out) {
    __shared__ float dls[16][260];                   // +4 pad
    int tid = threadIdx.x;
    int wid = tid >> 6, lane = tid & 63;
    int row = lane & 15, kq = lane >> 4;
    int m0 = blockIdx.x * 16;
    int n0 = blockIdx.y * 256;
    int col = n0 + lane * 4;

    // ---- issue epilogue loads early: they retire under the MFMA phase ----
    f32x4 bpre[4];
    #pragma unroll
    for (int r = 0; r < 4; ++r)
        bpre[r] = __builtin_nontemporal_load(
            (const f32x4*)(base + (size_t)(m0 + wid * 4 + r) * DOUT + col));
    f32x4 n2a = *(const f32x4*)(nrm2p + col);
    f32x4 n2b = *(const f32x4*)(nrm2p + DOUT + col);
    f32x4 n2c = *(const f32x4*)(nrm2p + 2 * DOUT + col);
    f32x4 n2d = *(const f32x4*)(nrm2p + 3 * DOUT + col);
    f32x4 mg  = *(const f32x4*)(mag + col);

    // ---- MFMA phase: delta = 2 * xa @ B^T for the 16x256 tile ----
    bf16x8 xb0 = *(const bf16x8*)(xabf + (size_t)(m0 + row) * RNK + kq * 8);
    bf16x8 xb1 = *(const bf16x8*)(xabf + (size_t)(m0 + row) * RNK + 32 + kq * 8);

    #pragma unroll
    for (int nt = 0; nt < 4; ++nt) {
        int n = n0 + wid * 64 + nt * 16;
        bf16x8 a0 = *(const bf16x8*)(Bbf + (size_t)(n + row) * RNK + kq * 8);
        bf16x8 a1 = *(const bf16x8*)(Bbf + (size_t)(n + row) * RNK + 32 + kq * 8);
        f32x4 acc = {0.f, 0.f, 0.f, 0.f};
        acc = MFMA16(a0, xb0, acc);                  // lane: delta[m=row][nloc = kq*4+rg]
        acc = MFMA16(a1, xb1, acc);
        *(f32x4*)&dls[row][wid * 64 + nt * 16 + kq * 4] = acc;
    }
    __syncthreads();

    // ---- per-thread mag_scale for this thread's 4 columns ----
    f32x4 msv;
    #pragma unroll
    for (int j = 0; j < 4; ++j)
        msv[j] = mg[j] / (sqrtf(n2a[j] + n2b[j] + n2c[j] + n2d[j]) + 1e-8f);

    #pragma unroll
    for (int r = 0; r < 4; ++r) {
        int m = wid * 4 + r;
        f32x4 d = *(const f32x4*)&dls[m][lane * 4];
        size_t gidx = (size_t)(m0 + m) * DOUT + col;
        f32x4 o;
        #pragma unroll
        for (int j = 0; j < 4; ++j) o[j] = (bpre[r][j] + 2.0f * d[j]) * msv[j];
        __builtin_nontemporal_store(o, (f32x4*)(out + gidx));
    }
}

extern "C" void kernel_launch(void* const* d_in, const int* in_sizes, int n_in,
                              void* d_out, int out_size, void* d_ws, size_t ws_size,
                              hipStream_t stream) {
    const float* x    = (const float*)d_in[0];   // [2,4096,4096]
    const float* base = (const float*)d_in[1];   // [2,4096,4096]
    const float* bw   = (const float*)d_in[2];   // [4096,4096]
    const float* lA   = (const float*)d_in[3];   // [64,4096]
    const float* lB   = (const float*)d_in[4];   // [4096,64]
    const float* mag  = (const float*)d_in[5];   // [4096]
    float* out = (float*)d_out;

    char* ws = (char*)d_ws;
    unsigned short* Abf  = (unsigned short*)(ws);                   // 512 KB (k1 only)
    unsigned short* Atbf = (unsigned short*)(ws + (512u << 10));    // 512 KB
    unsigned short* Bbf  = (unsigned short*)(ws + (1024u << 10));   // 512 KB
    unsigned short* xabf = (unsigned short*)(ws + (1536u << 10));   // 1 MB
    float*          nrm2p = (float*)(ws + (2560u << 10));           // 64 KB

    hipLaunchKernelGGL(k_prep, dim3(1024), dim3(256), 0, stream, lA, lB, Abf, Atbf, Bbf);
    hipLaunchKernelGGL(k1_xa, dim3(M_TOT / 16), dim3(512), 0, stream, x, Abf, xabf);
    hipLaunchKernelGGL(k2_norm, dim3((DOUT / 16) * 4), dim3(256), 0, stream,
                       bw, Bbf, Atbf, nrm2p);
    hipLaunchKernelGGL(k3_out, dim3(M_TOT / 16, DOUT / 256), dim3(256), 0, stream,
                       base, xabf, Bbf, nrm2p, mag, out);
}

// Round 4
// 163.088 us; speedup vs baseline: 1.0014x; 1.0014x over previous
//
#include <hip/hip_runtime.h>
#include <math.h>

typedef __bf16 bf16x8 __attribute__((ext_vector_type(8)));
typedef float f32x4 __attribute__((ext_vector_type(4)));

#define MFMA16(a, b, c) __builtin_amdgcn_mfma_f32_16x16x32_bf16(a, b, c, 0, 0, 0)

static constexpr int M_TOT = 8192;   // B*S
static constexpr int DIN = 4096;
static constexpr int DOUT = 4096;
static constexpr int RNK = 64;

__device__ inline unsigned short f2bf(float f) {
    union { float f; unsigned u; } v; v.f = f;
    unsigned r = v.u + 0x7FFFu + ((v.u >> 16) & 1u);   // round-to-nearest-even
    return (unsigned short)(r >> 16);
}

// ---------------------------------------------------------------------------
// Prep: lora_A [64][4096] -> Abf (bf16) and Atbf (bf16, [4096][64])
//       lora_B [4096][64] -> Bbf (bf16)
// ---------------------------------------------------------------------------
__global__ __launch_bounds__(256) void k_prep(const float* __restrict__ A,
                                              const float* __restrict__ B,
                                              unsigned short* __restrict__ Abf,
                                              unsigned short* __restrict__ Atbf,
                                              unsigned short* __restrict__ Bbf) {
    int i = blockIdx.x * 256 + threadIdx.x;          // 0 .. 262143
    unsigned short ab = f2bf(A[i]);
    Abf[i] = ab;
    int r = i >> 12, c = i & 4095;                   // A is [64][4096]
    Atbf[c * RNK + r] = ab;
    Bbf[i] = f2bf(B[i]);
}

// ---------------------------------------------------------------------------
// kA: ONE dispatch, two block roles (removes k1/k2 serialization + one ramp):
//   blocks 0..511   : xa = x @ lora_A^T for a 16-row m-tile (8-way K-split)
//   blocks 512..767 : mscale[o0..o0+15] = mag/(||bw_row + 2*(B@A)_row|| + eps)
//                     (8 waves x 512-i slices, full norm finished in-block)
// ---------------------------------------------------------------------------
__global__ __launch_bounds__(512) void kA(const float* __restrict__ x,
                                          const unsigned short* __restrict__ Abf,
                                          unsigned short* __restrict__ xabf,
                                          const float* __restrict__ bw,
                                          const unsigned short* __restrict__ Bbf,
                                          const unsigned short* __restrict__ Atbf,
                                          const float* __restrict__ mag,
                                          float* __restrict__ mscale) {
    __shared__ float red[8][1024];                   // k1 role: 32 KB reduce buffer
    int tid = threadIdx.x;
    int wid = tid >> 6, lane = tid & 63;
    int row = lane & 15, kq = lane >> 4;

    if (blockIdx.x < 512) {
        // ---------------- role 1: xa GEMM ----------------
        int m0 = blockIdx.x * 16;

        f32x4 acc0 = {0.f, 0.f, 0.f, 0.f};
        f32x4 acc1 = acc0, acc2 = acc0, acc3 = acc0;

        const float* xp = x + (size_t)(m0 + row) * DIN + wid * 512 + kq * 8;
        const unsigned short* ap = Abf + (size_t)row * DIN + wid * 512 + kq * 8;

        #pragma unroll 4
        for (int ks = 0; ks < 512; ks += 32) {
            f32x4 x0 = __builtin_nontemporal_load((const f32x4*)(xp + ks));
            f32x4 x1 = __builtin_nontemporal_load((const f32x4*)(xp + ks + 4));
            bf16x8 af;
            #pragma unroll
            for (int j = 0; j < 4; ++j) { af[j] = (__bf16)x0[j]; af[j + 4] = (__bf16)x1[j]; }
            acc0 = MFMA16(af, *(const bf16x8*)(ap + ks), acc0);
            acc1 = MFMA16(af, *(const bf16x8*)(ap + 16 * DIN + ks), acc1);
            acc2 = MFMA16(af, *(const bf16x8*)(ap + 32 * DIN + ks), acc2);
            acc3 = MFMA16(af, *(const bf16x8*)(ap + 48 * DIN + ks), acc3);
        }

        int mb = kq * 4;                              // C: row = (lane>>4)*4 + reg
        #pragma unroll
        for (int rg = 0; rg < 4; ++rg) {
            red[wid][(mb + rg) * 64 + row]      = acc0[rg];
            red[wid][(mb + rg) * 64 + 16 + row] = acc1[rg];
            red[wid][(mb + rg) * 64 + 32 + row] = acc2[rg];
            red[wid][(mb + rg) * 64 + 48 + row] = acc3[rg];
        }
        __syncthreads();

        #pragma unroll
        for (int e = tid; e < 1024; e += 512) {
            float s = 0.f;
            #pragma unroll
            for (int w = 0; w < 8; ++w) s += red[w][e];
            xabf[(size_t)m0 * RNK + e] = f2bf(s);
        }
    } else {
        // ---------------- role 2: DoRA norm + mscale ----------------
        int o0 = (blockIdx.x - 512) * 16;

        // B-operand: lora_B rows (o = lane&15), loop-invariant.
        bf16x8 b0 = *(const bf16x8*)(Bbf + (size_t)(o0 + row) * RNK + kq * 8);
        bf16x8 b1 = *(const bf16x8*)(Bbf + (size_t)(o0 + row) * RNK + 32 + kq * 8);

        f32x4 nacc = {0.f, 0.f, 0.f, 0.f};
        const float* bwp = bw + (size_t)(o0 + row) * DIN + wid * 512 + kq * 4;
        const unsigned short* atp = Atbf + (size_t)(wid * 512 + row) * RNK + kq * 8;

        #pragma unroll 4
        for (int ii = 0; ii < 32; ++ii) {
            bf16x8 a0 = *(const bf16x8*)(atp + (size_t)ii * 16 * RNK);
            bf16x8 a1 = *(const bf16x8*)(atp + (size_t)ii * 16 * RNK + 32);
            f32x4 d = {0.f, 0.f, 0.f, 0.f};
            d = MFMA16(a0, b0, d);                   // lane: delta[o=row][i = base+kq*4+rg]
            d = MFMA16(a1, b1, d);
            f32x4 wv = __builtin_nontemporal_load((const f32x4*)(bwp + ii * 16));
            #pragma unroll
            for (int rg = 0; rg < 4; ++rg) {
                float w = wv[rg] + 2.0f * d[rg];
                nacc[rg] += w * w;
            }
        }
        float ns = nacc[0] + nacc[1] + nacc[2] + nacc[3];

        // sum the 4 kq groups (lanes row, row+16, row+32, row+48)
        ns += __shfl_xor(ns, 16, 64);
        ns += __shfl_xor(ns, 32, 64);
        if (kq == 0) red[wid][row] = ns;
        __syncthreads();
        if (tid < 16) {
            float n2 = 0.f;
            #pragma unroll
            for (int w = 0; w < 8; ++w) n2 += red[w][tid];
            mscale[o0 + tid] = mag[o0 + tid] / (sqrtf(n2) + 1e-8f);
        }
    }
}

// ---------------------------------------------------------------------------
// kB: out = (base_output + 2 * xa @ lora_B^T) * mscale
// Block = 256 threads (4 waves), tile 16m x 256n; delta transposed through
// padded LDS; epilogue fully coalesced (1 KB/wave-instruction).
// ---------------------------------------------------------------------------
__global__ __launch_bounds__(256) void kB(const float* __restrict__ base,
                                          const unsigned short* __restrict__ xabf,
                                          const unsigned short* __restrict__ Bbf,
                                          const float* __restrict__ mscale,
                                          float* __restrict__ out) {
    __shared__ float dls[16][260];                   // +4 pad
    int tid = threadIdx.x;
    int wid = tid >> 6, lane = tid & 63;
    int row = lane & 15, kq = lane >> 4;
    int m0 = blockIdx.x * 16;
    int n0 = blockIdx.y * 256;
    int col = n0 + lane * 4;

    // issue epilogue loads early: they retire under the MFMA phase
    f32x4 bpre[4];
    #pragma unroll
    for (int r = 0; r < 4; ++r)
        bpre[r] = __builtin_nontemporal_load(
            (const f32x4*)(base + (size_t)(m0 + wid * 4 + r) * DOUT + col));
    f32x4 msv = *(const f32x4*)(mscale + col);

    // MFMA phase: delta = xa @ B^T for the 16x256 tile
    bf16x8 xb0 = *(const bf16x8*)(xabf + (size_t)(m0 + row) * RNK + kq * 8);
    bf16x8 xb1 = *(const bf16x8*)(xabf + (size_t)(m0 + row) * RNK + 32 + kq * 8);

    #pragma unroll
    for (int nt = 0; nt < 4; ++nt) {
        int n = n0 + wid * 64 + nt * 16;
        bf16x8 a0 = *(const bf16x8*)(Bbf + (size_t)(n + row) * RNK + kq * 8);
        bf16x8 a1 = *(const bf16x8*)(Bbf + (size_t)(n + row) * RNK + 32 + kq * 8);
        f32x4 acc = {0.f, 0.f, 0.f, 0.f};
        acc = MFMA16(a0, xb0, acc);                  // lane: delta[m=row][nloc = kq*4+rg]
        acc = MFMA16(a1, xb1, acc);
        *(f32x4*)&dls[row][wid * 64 + nt * 16 + kq * 4] = acc;
    }
    __syncthreads();

    #pragma unroll
    for (int r = 0; r < 4; ++r) {
        int m = wid * 4 + r;
        f32x4 d = *(const f32x4*)&dls[m][lane * 4];
        size_t gidx = (size_t)(m0 + m) * DOUT + col;
        f32x4 o;
        #pragma unroll
        for (int j = 0; j < 4; ++j) o[j] = (bpre[r][j] + 2.0f * d[j]) * msv[j];
        __builtin_nontemporal_store(o, (f32x4*)(out + gidx));
    }
}

extern "C" void kernel_launch(void* const* d_in, const int* in_sizes, int n_in,
                              void* d_out, int out_size, void* d_ws, size_t ws_size,
                              hipStream_t stream) {
    const float* x    = (const float*)d_in[0];   // [2,4096,4096]
    const float* base = (const float*)d_in[1];   // [2,4096,4096]
    const float* bw   = (const float*)d_in[2];   // [4096,4096]
    const float* lA   = (const float*)d_in[3];   // [64,4096]
    const float* lB   = (const float*)d_in[4];   // [4096,64]
    const float* mag  = (const float*)d_in[5];   // [4096]
    float* out = (float*)d_out;

    char* ws = (char*)d_ws;
    unsigned short* Abf  = (unsigned short*)(ws);                   // 512 KB
    unsigned short* Atbf = (unsigned short*)(ws + (512u << 10));    // 512 KB
    unsigned short* Bbf  = (unsigned short*)(ws + (1024u << 10));   // 512 KB
    unsigned short* xabf = (unsigned short*)(ws + (1536u << 10));   // 1 MB
    float*          msc  = (float*)(ws + (2560u << 10));            // 16 KB

    hipLaunchKernelGGL(k_prep, dim3(1024), dim3(256), 0, stream, lA, lB, Abf, Atbf, Bbf);
    hipLaunchKernelGGL(kA, dim3(512 + 256), dim3(512), 0, stream,
                       x, Abf, xabf, bw, Bbf, Atbf, mag, msc);
    hipLaunchKernelGGL(kB, dim3(M_TOT / 16, DOUT / 256), dim3(256), 0, stream,
                       base, xabf, Bbf, msc, out);
}

// Round 5
// 143.643 us; speedup vs baseline: 1.1370x; 1.1354x over previous
//
#include <hip/hip_runtime.h>
#include <math.h>

typedef __bf16 bf16x8 __attribute__((ext_vector_type(8)));
typedef float f32x4 __attribute__((ext_vector_type(4)));

#define MFMA16(a, b, c) __builtin_amdgcn_mfma_f32_16x16x32_bf16(a, b, c, 0, 0, 0)

static constexpr int M_TOT = 8192;   // B*S
static constexpr int DIN = 4096;
static constexpr int DOUT = 4096;
static constexpr int RNK = 64;

__device__ inline unsigned short f2bf(float f) {
    union { float f; unsigned u; } v; v.f = f;
    unsigned r = v.u + 0x7FFFu + ((v.u >> 16) & 1u);   // round-to-nearest-even
    return (unsigned short)(r >> 16);
}

// ---------------------------------------------------------------------------
// Prep: lora_A [64][4096] -> Abf (bf16) and Atbf (bf16, [4096][64])
//       lora_B [4096][64] -> Bbf (bf16)
// ---------------------------------------------------------------------------
__global__ __launch_bounds__(256) void k_prep(const float* __restrict__ A,
                                              const float* __restrict__ B,
                                              unsigned short* __restrict__ Abf,
                                              unsigned short* __restrict__ Atbf,
                                              unsigned short* __restrict__ Bbf) {
    int i = blockIdx.x * 256 + threadIdx.x;          // 0 .. 262143
    unsigned short ab = f2bf(A[i]);
    Abf[i] = ab;
    int r = i >> 12, c = i & 4095;                   // A is [64][4096]
    Atbf[c * RNK + r] = ab;
    Bbf[i] = f2bf(B[i]);
}

// ---------------------------------------------------------------------------
// kA: ONE dispatch, two block roles. Global loads are now fully coalesced
// (LDS-staged); fragment scatter happens in LDS, not at the HBM interface.
//   blocks 0..511   : xa = x @ lora_A^T for a 16-row m-tile
//   blocks 512..767 : mscale[o0..o0+15] = mag/(||bw_row + 2*(B@A)_row|| + eps)
// ---------------------------------------------------------------------------
__global__ __launch_bounds__(512) void kA(const float* __restrict__ x,
                                          const unsigned short* __restrict__ Abf,
                                          unsigned short* __restrict__ xabf,
                                          const float* __restrict__ bw,
                                          const unsigned short* __restrict__ Bbf,
                                          const unsigned short* __restrict__ Atbf,
                                          const float* __restrict__ mag,
                                          float* __restrict__ mscale) {
    __shared__ __align__(16) char smem[33792];
    int tid = threadIdx.x;
    int wid = tid >> 6, lane = tid & 63;
    int row = lane & 15, kq = lane >> 4;

    if (blockIdx.x < 512) {
        // ---------------- role 1: xa GEMM, LDS-staged x ----------------
        unsigned short (*stage)[520] = (unsigned short (*)[520])smem;  // 16.6 KB
        float (*red)[1024] = (float (*)[1024])smem;                    // 32 KB (after loop)
        int m0 = blockIdx.x * 16;
        int sr = tid >> 5, sc = (tid & 31) * 4;       // staging: 32 threads/row
        const float* xrow = x + (size_t)(m0 + sr) * DIN + sc;

        f32x4 acc0 = {0.f, 0.f, 0.f, 0.f};
        f32x4 acc1 = acc0, acc2 = acc0, acc3 = acc0;

        for (int c = 0; c < 8; ++c) {                 // K chunks of 512
            #pragma unroll
            for (int rep = 0; rep < 4; ++rep) {
                f32x4 v = __builtin_nontemporal_load(
                    (const f32x4*)(xrow + c * 512 + rep * 128));
                ushort4 h;
                h.x = f2bf(v[0]); h.y = f2bf(v[1]); h.z = f2bf(v[2]); h.w = f2bf(v[3]);
                *(ushort4*)&stage[sr][rep * 128 + sc] = h;
            }
            __syncthreads();
            #pragma unroll
            for (int s = 0; s < 2; ++s) {             // wave's K=64 slice, 2 steps
                int k0 = wid * 64 + s * 32;
                bf16x8 af = *(const bf16x8*)&stage[row][k0 + kq * 8];
                const unsigned short* ap = Abf + (size_t)row * DIN + c * 512 + k0 + kq * 8;
                acc0 = MFMA16(af, *(const bf16x8*)(ap), acc0);
                acc1 = MFMA16(af, *(const bf16x8*)(ap + 16 * DIN), acc1);
                acc2 = MFMA16(af, *(const bf16x8*)(ap + 32 * DIN), acc2);
                acc3 = MFMA16(af, *(const bf16x8*)(ap + 48 * DIN), acc3);
            }
            __syncthreads();
        }

        // cross-wave reduce (red aliases stage; all stage reads are done)
        int mb = kq * 4;                              // C: row = (lane>>4)*4 + reg
        #pragma unroll
        for (int rg = 0; rg < 4; ++rg) {
            red[wid][(mb + rg) * 64 + row]      = acc0[rg];
            red[wid][(mb + rg) * 64 + 16 + row] = acc1[rg];
            red[wid][(mb + rg) * 64 + 32 + row] = acc2[rg];
            red[wid][(mb + rg) * 64 + 48 + row] = acc3[rg];
        }
        __syncthreads();
        #pragma unroll
        for (int e = tid; e < 1024; e += 512) {
            float s = 0.f;
            #pragma unroll
            for (int w = 0; w < 8; ++w) s += red[w][e];
            xabf[(size_t)m0 * RNK + e] = f2bf(s);
        }
    } else {
        // ---------------- role 2: DoRA norm, LDS-staged bw ----------------
        float (*stagef)[260] = (float (*)[260])smem;  // 16.6 KB
        float (*part)[16] = (float (*)[16])(smem + 17408);
        int o0 = (blockIdx.x - 512) * 16;

        bf16x8 b0 = *(const bf16x8*)(Bbf + (size_t)(o0 + row) * RNK + kq * 8);
        bf16x8 b1 = *(const bf16x8*)(Bbf + (size_t)(o0 + row) * RNK + 32 + kq * 8);

        f32x4 nacc = {0.f, 0.f, 0.f, 0.f};
        int sr = tid >> 5, sc = (tid & 31) * 4;
        const float* bwrow = bw + (size_t)(o0 + sr) * DIN + sc;

        for (int c = 0; c < 16; ++c) {                // i chunks of 256
            #pragma unroll
            for (int rep = 0; rep < 2; ++rep) {
                f32x4 v = __builtin_nontemporal_load(
                    (const f32x4*)(bwrow + c * 256 + rep * 128));
                *(f32x4*)&stagef[sr][rep * 128 + sc] = v;
            }
            __syncthreads();
            #pragma unroll
            for (int g = 0; g < 2; ++g) {             // wave's i=32 slice, 2 groups
                int iloc = wid * 32 + g * 16;
                const unsigned short* atp =
                    Atbf + (size_t)(c * 256 + iloc + row) * RNK + kq * 8;
                bf16x8 a0 = *(const bf16x8*)(atp);
                bf16x8 a1 = *(const bf16x8*)(atp + 32);
                f32x4 d = {0.f, 0.f, 0.f, 0.f};
                d = MFMA16(a0, b0, d);                // lane: delta[o=o0+row][i=base+kq*4+rg]
                d = MFMA16(a1, b1, d);
                f32x4 wv = *(const f32x4*)&stagef[row][iloc + kq * 4];
                #pragma unroll
                for (int rg = 0; rg < 4; ++rg) {
                    float w = wv[rg] + 2.0f * d[rg];
                    nacc[rg] += w * w;
                }
            }
            __syncthreads();
        }
        float ns = nacc[0] + nacc[1] + nacc[2] + nacc[3];
        ns += __shfl_xor(ns, 16, 64);
        ns += __shfl_xor(ns, 32, 64);
        if (kq == 0) part[wid][row] = ns;
        __syncthreads();
        if (tid < 16) {
            float n2 = 0.f;
            #pragma unroll
            for (int w = 0; w < 8; ++w) n2 += part[w][tid];
            mscale[o0 + tid] = mag[o0 + tid] / (sqrtf(n2) + 1e-8f);
        }
    }
}

// ---------------------------------------------------------------------------
// kB: out = (base_output + 2 * xa @ lora_B^T) * mscale
// Block = 256 threads (4 waves), TWO 16m x 256n tiles (B-frags + mscale
// reused); delta transposed through padded LDS; epilogue fully coalesced.
// ---------------------------------------------------------------------------
__global__ __launch_bounds__(256) void kB(const float* __restrict__ base,
                                          const unsigned short* __restrict__ xabf,
                                          const unsigned short* __restrict__ Bbf,
                                          const float* __restrict__ mscale,
                                          float* __restrict__ out) {
    __shared__ float dls[32][260];                   // 33.3 KB, +4 pad
    int tid = threadIdx.x;
    int wid = tid >> 6, lane = tid & 63;
    int row = lane & 15, kq = lane >> 4;
    int m0 = blockIdx.x * 32;
    int n0 = blockIdx.y * 256;
    int col = n0 + lane * 4;

    // issue epilogue loads early: they retire under the MFMA phase
    f32x4 bpre[2][4];
    #pragma unroll
    for (int h = 0; h < 2; ++h)
        #pragma unroll
        for (int r = 0; r < 4; ++r)
            bpre[h][r] = __builtin_nontemporal_load(
                (const f32x4*)(base + (size_t)(m0 + h * 16 + wid * 4 + r) * DOUT + col));
    f32x4 msv = *(const f32x4*)(mscale + col);

    // MFMA phase: delta = xa @ B^T for two 16x256 tiles
    bf16x8 xb0[2], xb1[2];
    #pragma unroll
    for (int h = 0; h < 2; ++h) {
        xb0[h] = *(const bf16x8*)(xabf + (size_t)(m0 + h * 16 + row) * RNK + kq * 8);
        xb1[h] = *(const bf16x8*)(xabf + (size_t)(m0 + h * 16 + row) * RNK + 32 + kq * 8);
    }

    #pragma unroll
    for (int nt = 0; nt < 4; ++nt) {
        int n = n0 + wid * 64 + nt * 16;
        bf16x8 a0 = *(const bf16x8*)(Bbf + (size_t)(n + row) * RNK + kq * 8);
        bf16x8 a1 = *(const bf16x8*)(Bbf + (size_t)(n + row) * RNK + 32 + kq * 8);
        #pragma unroll
        for (int h = 0; h < 2; ++h) {
            f32x4 acc = {0.f, 0.f, 0.f, 0.f};
            acc = MFMA16(a0, xb0[h], acc);           // lane: delta[m=row][nloc=kq*4+rg]
            acc = MFMA16(a1, xb1[h], acc);
            *(f32x4*)&dls[h * 16 + row][wid * 64 + nt * 16 + kq * 4] = acc;
        }
    }
    __syncthreads();

    #pragma unroll
    for (int h = 0; h < 2; ++h)
        #pragma unroll
        for (int r = 0; r < 4; ++r) {
            int m = h * 16 + wid * 4 + r;
            f32x4 d = *(const f32x4*)&dls[m][lane * 4];
            size_t gidx = (size_t)(m0 + m) * DOUT + col;
            f32x4 o;
            #pragma unroll
            for (int j = 0; j < 4; ++j) o[j] = (bpre[h][r][j] + 2.0f * d[j]) * msv[j];
            __builtin_nontemporal_store(o, (f32x4*)(out + gidx));
        }
}

extern "C" void kernel_launch(void* const* d_in, const int* in_sizes, int n_in,
                              void* d_out, int out_size, void* d_ws, size_t ws_size,
                              hipStream_t stream) {
    const float* x    = (const float*)d_in[0];   // [2,4096,4096]
    const float* base = (const float*)d_in[1];   // [2,4096,4096]
    const float* bw   = (const float*)d_in[2];   // [4096,4096]
    const float* lA   = (const float*)d_in[3];   // [64,4096]
    const float* lB   = (const float*)d_in[4];   // [4096,64]
    const float* mag  = (const float*)d_in[5];   // [4096]
    float* out = (float*)d_out;

    char* ws = (char*)d_ws;
    unsigned short* Abf  = (unsigned short*)(ws);                   // 512 KB
    unsigned short* Atbf = (unsigned short*)(ws + (512u << 10));    // 512 KB
    unsigned short* Bbf  = (unsigned short*)(ws + (1024u << 10));   // 512 KB
    unsigned short* xabf = (unsigned short*)(ws + (1536u << 10));   // 1 MB
    float*          msc  = (float*)(ws + (2560u << 10));            // 16 KB

    hipLaunchKernelGGL(k_prep, dim3(1024), dim3(256), 0, stream, lA, lB, Abf, Atbf, Bbf);
    hipLaunchKernelGGL(kA, dim3(512 + 256), dim3(512), 0, stream,
                       x, Abf, xabf, bw, Bbf, Atbf, mag, msc);
    hipLaunchKernelGGL(kB, dim3(M_TOT / 32, DOUT / 256), dim3(256), 0, stream,
                       base, xabf, Bbf, msc, out);
}

// Round 6
// 136.653 us; speedup vs baseline: 1.1952x; 1.0512x over previous
//
#include <hip/hip_runtime.h>
#include <math.h>

typedef __bf16 bf16x8 __attribute__((ext_vector_type(8)));
typedef float f32x4 __attribute__((ext_vector_type(4)));

#define MFMA16(a, b, c) __builtin_amdgcn_mfma_f32_16x16x32_bf16(a, b, c, 0, 0, 0)

static constexpr int M_TOT = 8192;   // B*S
static constexpr int DIN = 4096;
static constexpr int DOUT = 4096;
static constexpr int RNK = 64;

__device__ inline unsigned short f2bf(float f) {
    union { float f; unsigned u; } v; v.f = f;
    unsigned r = v.u + 0x7FFFu + ((v.u >> 16) & 1u);   // round-to-nearest-even
    return (unsigned short)(r >> 16);
}

// ---------------------------------------------------------------------------
// Prep: lora_A [64][4096] -> Abf (bf16) and Atbf (bf16, [4096][64])
//       lora_B [4096][64] -> Bbf (bf16)
// ---------------------------------------------------------------------------
__global__ __launch_bounds__(256) void k_prep(const float* __restrict__ A,
                                              const float* __restrict__ B,
                                              unsigned short* __restrict__ Abf,
                                              unsigned short* __restrict__ Atbf,
                                              unsigned short* __restrict__ Bbf) {
    int i = blockIdx.x * 256 + threadIdx.x;          // 0 .. 262143
    unsigned short ab = f2bf(A[i]);
    Abf[i] = ab;
    int r = i >> 12, c = i & 4095;                   // A is [64][4096]
    Atbf[c * RNK + r] = ab;
    Bbf[i] = f2bf(B[i]);
}

// ---------------------------------------------------------------------------
// kA: ONE dispatch, two block roles, register-double-buffered LDS staging:
//   per chunk: barrier -> ds_write(regs of chunk c) -> issue loads(c+1)
//              -> barrier -> ds_read+MFMA(chunk c).
// Loads stay in flight across the compute phase (T14); no vmcnt(0)-before-
// compute bursts. No nontemporal on loads (let L2/L3 serve).
//   blocks 0..511   : xa = x @ lora_A^T for a 16-row m-tile
//   blocks 512..767 : mscale[o0..o0+15] = mag/(||bw_row + 2*(B@A)_row|| + eps)
// ---------------------------------------------------------------------------
__global__ __launch_bounds__(512, 6) void kA(const float* __restrict__ x,
                                             const unsigned short* __restrict__ Abf,
                                             unsigned short* __restrict__ xabf,
                                             const float* __restrict__ bw,
                                             const unsigned short* __restrict__ Bbf,
                                             const unsigned short* __restrict__ Atbf,
                                             const float* __restrict__ mag,
                                             float* __restrict__ mscale) {
    __shared__ __align__(16) char smem[33792];
    int tid = threadIdx.x;
    int wid = tid >> 6, lane = tid & 63;
    int row = lane & 15, kq = lane >> 4;
    int sr = tid >> 5, sc = (tid & 31) * 4;           // staging: 32 threads/row

    if (blockIdx.x < 512) {
        // ---------------- role 1: xa GEMM, reg-dbuf staged x ----------------
        unsigned short (*stage)[520] = (unsigned short (*)[520])smem;  // 16.6 KB
        float (*red)[1024] = (float (*)[1024])smem;                    // 32 KB (after loop)
        int m0 = blockIdx.x * 16;
        const float* xrow = x + (size_t)(m0 + sr) * DIN + sc;

        f32x4 acc0 = {0.f, 0.f, 0.f, 0.f};
        f32x4 acc1 = acc0, acc2 = acc0, acc3 = acc0;

        // prologue: chunk 0 into regs
        f32x4 r0 = *(const f32x4*)(xrow);
        f32x4 r1 = *(const f32x4*)(xrow + 128);
        f32x4 r2 = *(const f32x4*)(xrow + 256);
        f32x4 r3 = *(const f32x4*)(xrow + 384);

        for (int c = 0; c < 8; ++c) {                 // K chunks of 512
            __syncthreads();                          // prior LDS reads done
            ushort4 h;
            h.x = f2bf(r0[0]); h.y = f2bf(r0[1]); h.z = f2bf(r0[2]); h.w = f2bf(r0[3]);
            *(ushort4*)&stage[sr][sc] = h;
            h.x = f2bf(r1[0]); h.y = f2bf(r1[1]); h.z = f2bf(r1[2]); h.w = f2bf(r1[3]);
            *(ushort4*)&stage[sr][128 + sc] = h;
            h.x = f2bf(r2[0]); h.y = f2bf(r2[1]); h.z = f2bf(r2[2]); h.w = f2bf(r2[3]);
            *(ushort4*)&stage[sr][256 + sc] = h;
            h.x = f2bf(r3[0]); h.y = f2bf(r3[1]); h.z = f2bf(r3[2]); h.w = f2bf(r3[3]);
            *(ushort4*)&stage[sr][384 + sc] = h;
            if (c < 7) {                              // issue c+1 loads; retire under compute
                const float* nx = xrow + (c + 1) * 512;
                r0 = *(const f32x4*)(nx);
                r1 = *(const f32x4*)(nx + 128);
                r2 = *(const f32x4*)(nx + 256);
                r3 = *(const f32x4*)(nx + 384);
            }
            __syncthreads();                          // stage visible
            #pragma unroll
            for (int s = 0; s < 2; ++s) {             // wave's K=64 slice, 2 steps
                int k0 = wid * 64 + s * 32;
                bf16x8 af = *(const bf16x8*)&stage[row][k0 + kq * 8];
                const unsigned short* ap = Abf + (size_t)row * DIN + c * 512 + k0 + kq * 8;
                acc0 = MFMA16(af, *(const bf16x8*)(ap), acc0);
                acc1 = MFMA16(af, *(const bf16x8*)(ap + 16 * DIN), acc1);
                acc2 = MFMA16(af, *(const bf16x8*)(ap + 32 * DIN), acc2);
                acc3 = MFMA16(af, *(const bf16x8*)(ap + 48 * DIN), acc3);
            }
        }
        __syncthreads();

        // cross-wave reduce (red aliases stage; all stage reads are done)
        int mb = kq * 4;                              // C: row = (lane>>4)*4 + reg
        #pragma unroll
        for (int rg = 0; rg < 4; ++rg) {
            red[wid][(mb + rg) * 64 + row]      = acc0[rg];
            red[wid][(mb + rg) * 64 + 16 + row] = acc1[rg];
            red[wid][(mb + rg) * 64 + 32 + row] = acc2[rg];
            red[wid][(mb + rg) * 64 + 48 + row] = acc3[rg];
        }
        __syncthreads();
        #pragma unroll
        for (int e = tid; e < 1024; e += 512) {
            float s = 0.f;
            #pragma unroll
            for (int w = 0; w < 8; ++w) s += red[w][e];
            xabf[(size_t)m0 * RNK + e] = f2bf(s);
        }
    } else {
        // ---------------- role 2: DoRA norm, reg-dbuf staged bw ----------------
        float (*stagef)[516] = (float (*)[516])smem;  // 33 KB
        float (*part)[16] = (float (*)[16])(smem + 33024);
        int o0 = (blockIdx.x - 512) * 16;

        bf16x8 b0 = *(const bf16x8*)(Bbf + (size_t)(o0 + row) * RNK + kq * 8);
        bf16x8 b1 = *(const bf16x8*)(Bbf + (size_t)(o0 + row) * RNK + 32 + kq * 8);

        f32x4 nacc = {0.f, 0.f, 0.f, 0.f};
        const float* bwrow = bw + (size_t)(o0 + sr) * DIN + sc;

        // prologue: chunk 0 into regs
        f32x4 q0 = *(const f32x4*)(bwrow);
        f32x4 q1 = *(const f32x4*)(bwrow + 128);
        f32x4 q2 = *(const f32x4*)(bwrow + 256);
        f32x4 q3 = *(const f32x4*)(bwrow + 384);

        for (int c = 0; c < 8; ++c) {                 // i chunks of 512
            __syncthreads();
            *(f32x4*)&stagef[sr][sc]       = q0;
            *(f32x4*)&stagef[sr][128 + sc] = q1;
            *(f32x4*)&stagef[sr][256 + sc] = q2;
            *(f32x4*)&stagef[sr][384 + sc] = q3;
            if (c < 7) {
                const float* nb = bwrow + (c + 1) * 512;
                q0 = *(const f32x4*)(nb);
                q1 = *(const f32x4*)(nb + 128);
                q2 = *(const f32x4*)(nb + 256);
                q3 = *(const f32x4*)(nb + 384);
            }
            __syncthreads();
            #pragma unroll
            for (int g = 0; g < 4; ++g) {             // wave's i=64 slice, 4 groups
                int iloc = wid * 64 + g * 16;
                const unsigned short* atp =
                    Atbf + (size_t)(c * 512 + iloc + row) * RNK + kq * 8;
                bf16x8 a0 = *(const bf16x8*)(atp);
                bf16x8 a1 = *(const bf16x8*)(atp + 32);
                f32x4 d = {0.f, 0.f, 0.f, 0.f};
                d = MFMA16(a0, b0, d);                // lane: delta[o=o0+row][i=base+kq*4+rg]
                d = MFMA16(a1, b1, d);
                f32x4 wv = *(const f32x4*)&stagef[row][iloc + kq * 4];
                #pragma unroll
                for (int rg = 0; rg < 4; ++rg) {
                    float w = wv[rg] + 2.0f * d[rg];
                    nacc[rg] += w * w;
                }
            }
        }
        float ns = nacc[0] + nacc[1] + nacc[2] + nacc[3];
        ns += __shfl_xor(ns, 16, 64);
        ns += __shfl_xor(ns, 32, 64);
        if (kq == 0) part[wid][row] = ns;
        __syncthreads();
        if (tid < 16) {
            float n2 = 0.f;
            #pragma unroll
            for (int w = 0; w < 8; ++w) n2 += part[w][tid];
            mscale[o0 + tid] = mag[o0 + tid] / (sqrtf(n2) + 1e-8f);
        }
    }
}

// ---------------------------------------------------------------------------
// kB: out = (base_output + 2 * xa @ lora_B^T) * mscale   (unchanged)
// ---------------------------------------------------------------------------
__global__ __launch_bounds__(256) void kB(const float* __restrict__ base,
                                          const unsigned short* __restrict__ xabf,
                                          const unsigned short* __restrict__ Bbf,
                                          const float* __restrict__ mscale,
                                          float* __restrict__ out) {
    __shared__ float dls[32][260];                   // 33.3 KB, +4 pad
    int tid = threadIdx.x;
    int wid = tid >> 6, lane = tid & 63;
    int row = lane & 15, kq = lane >> 4;
    int m0 = blockIdx.x * 32;
    int n0 = blockIdx.y * 256;
    int col = n0 + lane * 4;

    // issue epilogue loads early: they retire under the MFMA phase
    f32x4 bpre[2][4];
    #pragma unroll
    for (int h = 0; h < 2; ++h)
        #pragma unroll
        for (int r = 0; r < 4; ++r)
            bpre[h][r] = __builtin_nontemporal_load(
                (const f32x4*)(base + (size_t)(m0 + h * 16 + wid * 4 + r) * DOUT + col));
    f32x4 msv = *(const f32x4*)(mscale + col);

    // MFMA phase: delta = xa @ B^T for two 16x256 tiles
    bf16x8 xb0[2], xb1[2];
    #pragma unroll
    for (int h = 0; h < 2; ++h) {
        xb0[h] = *(const bf16x8*)(xabf + (size_t)(m0 + h * 16 + row) * RNK + kq * 8);
        xb1[h] = *(const bf16x8*)(xabf + (size_t)(m0 + h * 16 + row) * RNK + 32 + kq * 8);
    }

    #pragma unroll
    for (int nt = 0; nt < 4; ++nt) {
        int n = n0 + wid * 64 + nt * 16;
        bf16x8 a0 = *(const bf16x8*)(Bbf + (size_t)(n + row) * RNK + kq * 8);
        bf16x8 a1 = *(const bf16x8*)(Bbf + (size_t)(n + row) * RNK + 32 + kq * 8);
        #pragma unroll
        for (int h = 0; h < 2; ++h) {
            f32x4 acc = {0.f, 0.f, 0.f, 0.f};
            acc = MFMA16(a0, xb0[h], acc);           // lane: delta[m=row][nloc=kq*4+rg]
            acc = MFMA16(a1, xb1[h], acc);
            *(f32x4*)&dls[h * 16 + row][wid * 64 + nt * 16 + kq * 4] = acc;
        }
    }
    __syncthreads();

    #pragma unroll
    for (int h = 0; h < 2; ++h)
        #pragma unroll
        for (int r = 0; r < 4; ++r) {
            int m = h * 16 + wid * 4 + r;
            f32x4 d = *(const f32x4*)&dls[m][lane * 4];
            size_t gidx = (size_t)(m0 + m) * DOUT + col;
            f32x4 o;
            #pragma unroll
            for (int j = 0; j < 4; ++j) o[j] = (bpre[h][r][j] + 2.0f * d[j]) * msv[j];
            __builtin_nontemporal_store(o, (f32x4*)(out + gidx));
        }
}

extern "C" void kernel_launch(void* const* d_in, const int* in_sizes, int n_in,
                              void* d_out, int out_size, void* d_ws, size_t ws_size,
                              hipStream_t stream) {
    const float* x    = (const float*)d_in[0];   // [2,4096,4096]
    const float* base = (const float*)d_in[1];   // [2,4096,4096]
    const float* bw   = (const float*)d_in[2];   // [4096,4096]
    const float* lA   = (const float*)d_in[3];   // [64,4096]
    const float* lB   = (const float*)d_in[4];   // [4096,64]
    const float* mag  = (const float*)d_in[5];   // [4096]
    float* out = (float*)d_out;

    char* ws = (char*)d_ws;
    unsigned short* Abf  = (unsigned short*)(ws);                   // 512 KB
    unsigned short* Atbf = (unsigned short*)(ws + (512u << 10));    // 512 KB
    unsigned short* Bbf  = (unsigned short*)(ws + (1024u << 10));   // 512 KB
    unsigned short* xabf = (unsigned short*)(ws + (1536u << 10));   // 1 MB
    float*          msc  = (float*)(ws + (2560u << 10));            // 16 KB

    hipLaunchKernelGGL(k_prep, dim3(1024), dim3(256), 0, stream, lA, lB, Abf, Atbf, Bbf);
    hipLaunchKernelGGL(kA, dim3(512 + 256), dim3(512), 0, stream,
                       x, Abf, xabf, bw, Bbf, Atbf, mag, msc);
    hipLaunchKernelGGL(kB, dim3(M_TOT / 32, DOUT / 256), dim3(256), 0, stream,
                       base, xabf, Bbf, msc, out);
}

// Round 7
// 112.124 us; speedup vs baseline: 1.4566x; 1.2188x over previous
//
#include <hip/hip_runtime.h>
#include <math.h>

typedef __bf16 bf16x8 __attribute__((ext_vector_type(8)));
typedef float f32x4 __attribute__((ext_vector_type(4)));

#define MFMA16(a, b, c) __builtin_amdgcn_mfma_f32_16x16x32_bf16(a, b, c, 0, 0, 0)

static constexpr int M_TOT = 8192;   // B*S
static constexpr int DIN = 4096;
static constexpr int DOUT = 4096;
static constexpr int RNK = 64;

__device__ inline unsigned short f2bf(float f) {
    union { float f; unsigned u; } v; v.f = f;
    unsigned r = v.u + 0x7FFFu + ((v.u >> 16) & 1u);   // round-to-nearest-even
    return (unsigned short)(r >> 16);
}

// ---------------------------------------------------------------------------
// Fragment-major layout: for a [rows][cols] bf16 operand consumed by MFMA as
// 16-row tiles x 32-col k-slices, fragment block (tile,slice) holds the 64
// lanes' bf16x8 contiguously: addr = (block_id*512) + (kq*16 + row)*8 + j
// where lane = kq*16+row, col = slice*32 + kq*8 + j.
// Every wave fragment load = one coalesced 1 KB instruction (16 B/lane).
//
// k_prep: lora_A [64][4096] -> Afrag  (block = ks*4 + nt,  512 KB)
//                              Atfrag (A^T: block = it*2 + rs, 512 KB)
//         lora_B [4096][64] -> Bfrag  (block = ot*2 + rs, 512 KB)
// ---------------------------------------------------------------------------
__global__ __launch_bounds__(256) void k_prep(const float* __restrict__ A,
                                              const float* __restrict__ B,
                                              unsigned short* __restrict__ Afrag,
                                              unsigned short* __restrict__ Atfrag,
                                              unsigned short* __restrict__ Bfrag) {
    int i = blockIdx.x * 256 + threadIdx.x;          // 0 .. 262143
    unsigned short ab = f2bf(A[i]);
    int n = i >> 12, k = i & 4095;                   // A[n][k]
    // Afrag: fragment (nt = n>>4, ks = k>>5)
    Afrag[(((k >> 5) << 2) + (n >> 4)) * 512 +
          ((((k >> 3) & 3) << 4) + (n & 15)) * 8 + (k & 7)] = ab;
    // Atfrag: At[i=k][r=n], fragment (it = k>>4, rs = n>>5)
    Atfrag[(((k >> 4) << 1) + (n >> 5)) * 512 +
           ((((n >> 3) & 3) << 4) + (k & 15)) * 8 + (n & 7)] = ab;
    // Bfrag: B[o][r], fragment (ot = o>>4, rs = r>>5)
    unsigned short bb = f2bf(B[i]);
    int o = i >> 6, r = i & 63;
    Bfrag[(((o >> 4) << 1) + (r >> 5)) * 512 +
          ((((r >> 3) & 3) << 4) + (o & 15)) * 8 + (r & 7)] = bb;
}

// ---------------------------------------------------------------------------
// kA: ONE dispatch, two block roles, reg-dbuf LDS staging for the fp32
// stream; ALL bf16 operands from fragment-major arrays (coalesced, L2-res).
//   blocks 0..511   : xa = x @ lora_A^T for a 16-row m-tile (frag-major out)
//   blocks 512..767 : mscale[o0..15] = mag/(||bw_row + 2*(B@A)_row|| + eps)
// ---------------------------------------------------------------------------
__global__ __launch_bounds__(512, 6) void kA(const float* __restrict__ x,
                                             const unsigned short* __restrict__ Afrag,
                                             unsigned short* __restrict__ xafrag,
                                             const float* __restrict__ bw,
                                             const unsigned short* __restrict__ Bfrag,
                                             const unsigned short* __restrict__ Atfrag,
                                             const float* __restrict__ mag,
                                             float* __restrict__ mscale) {
    __shared__ __align__(16) char smem[33792];
    int tid = threadIdx.x;
    int wid = tid >> 6, lane = tid & 63;
    int row = lane & 15, kq = lane >> 4;
    int sr = tid >> 5, sc = (tid & 31) * 4;           // staging: 32 threads/row
    int lane8 = lane * 8;

    if (blockIdx.x < 512) {
        // ---------------- role 1: xa GEMM ----------------
        unsigned short (*stage)[520] = (unsigned short (*)[520])smem;  // 16.6 KB
        float (*red)[1024] = (float (*)[1024])smem;                    // 32 KB (after loop)
        int m0 = blockIdx.x * 16;
        const float* xrow = x + (size_t)(m0 + sr) * DIN + sc;

        f32x4 acc0 = {0.f, 0.f, 0.f, 0.f};
        f32x4 acc1 = acc0, acc2 = acc0, acc3 = acc0;

        f32x4 r0 = *(const f32x4*)(xrow);
        f32x4 r1 = *(const f32x4*)(xrow + 128);
        f32x4 r2 = *(const f32x4*)(xrow + 256);
        f32x4 r3 = *(const f32x4*)(xrow + 384);

        for (int c = 0; c < 8; ++c) {                 // K chunks of 512
            __syncthreads();                          // prior LDS reads done
            ushort4 h;
            h.x = f2bf(r0[0]); h.y = f2bf(r0[1]); h.z = f2bf(r0[2]); h.w = f2bf(r0[3]);
            *(ushort4*)&stage[sr][sc] = h;
            h.x = f2bf(r1[0]); h.y = f2bf(r1[1]); h.z = f2bf(r1[2]); h.w = f2bf(r1[3]);
            *(ushort4*)&stage[sr][128 + sc] = h;
            h.x = f2bf(r2[0]); h.y = f2bf(r2[1]); h.z = f2bf(r2[2]); h.w = f2bf(r2[3]);
            *(ushort4*)&stage[sr][256 + sc] = h;
            h.x = f2bf(r3[0]); h.y = f2bf(r3[1]); h.z = f2bf(r3[2]); h.w = f2bf(r3[3]);
            *(ushort4*)&stage[sr][384 + sc] = h;
            if (c < 7) {                              // issue c+1 loads; retire under compute
                const float* nx = xrow + (c + 1) * 512;
                r0 = *(const f32x4*)(nx);
                r1 = *(const f32x4*)(nx + 128);
                r2 = *(const f32x4*)(nx + 256);
                r3 = *(const f32x4*)(nx + 384);
            }
            __syncthreads();                          // stage visible
            #pragma unroll
            for (int s = 0; s < 2; ++s) {             // wave's K=64 slice, 2 steps
                int k0 = wid * 64 + s * 32;
                bf16x8 af = *(const bf16x8*)&stage[row][k0 + kq * 8];
                int ks = (c * 512 + k0) >> 5;
                const unsigned short* ap = Afrag + (size_t)(ks << 2) * 512 + lane8;
                acc0 = MFMA16(af, *(const bf16x8*)(ap), acc0);
                acc1 = MFMA16(af, *(const bf16x8*)(ap + 512), acc1);
                acc2 = MFMA16(af, *(const bf16x8*)(ap + 1024), acc2);
                acc3 = MFMA16(af, *(const bf16x8*)(ap + 1536), acc3);
            }
        }
        __syncthreads();

        // cross-wave reduce (red aliases stage; all stage reads are done)
        int mb = kq * 4;                              // C: row = (lane>>4)*4 + reg
        #pragma unroll
        for (int rg = 0; rg < 4; ++rg) {
            red[wid][(mb + rg) * 64 + row]      = acc0[rg];
            red[wid][(mb + rg) * 64 + 16 + row] = acc1[rg];
            red[wid][(mb + rg) * 64 + 32 + row] = acc2[rg];
            red[wid][(mb + rg) * 64 + 48 + row] = acc3[rg];
        }
        __syncthreads();
        #pragma unroll
        for (int e = tid; e < 1024; e += 512) {
            float s = 0.f;
            #pragma unroll
            for (int w = 0; w < 8; ++w) s += red[w][e];
            int ml = e >> 6, r = e & 63;              // xa[m0+ml][r] -> fragment-major
            xafrag[((size_t)blockIdx.x * 2 + (r >> 5)) * 512 +
                   ((((r >> 3) & 3) << 4) + ml) * 8 + (r & 7)] = f2bf(s);
        }
    } else {
        // ---------------- role 2: DoRA norm ----------------
        float (*stagef)[516] = (float (*)[516])smem;  // 33 KB
        float (*part)[16] = (float (*)[16])(smem + 33024);
        int o0 = (blockIdx.x - 512) * 16;
        int ot = o0 >> 4;

        bf16x8 b0 = *(const bf16x8*)(Bfrag + (size_t)(ot * 2) * 512 + lane8);
        bf16x8 b1 = *(const bf16x8*)(Bfrag + (size_t)(ot * 2 + 1) * 512 + lane8);

        f32x4 nacc = {0.f, 0.f, 0.f, 0.f};
        const float* bwrow = bw + (size_t)(o0 + sr) * DIN + sc;

        f32x4 q0 = *(const f32x4*)(bwrow);
        f32x4 q1 = *(const f32x4*)(bwrow + 128);
        f32x4 q2 = *(const f32x4*)(bwrow + 256);
        f32x4 q3 = *(const f32x4*)(bwrow + 384);

        for (int c = 0; c < 8; ++c) {                 // i chunks of 512
            __syncthreads();
            *(f32x4*)&stagef[sr][sc]       = q0;
            *(f32x4*)&stagef[sr][128 + sc] = q1;
            *(f32x4*)&stagef[sr][256 + sc] = q2;
            *(f32x4*)&stagef[sr][384 + sc] = q3;
            if (c < 7) {
                const float* nb = bwrow + (c + 1) * 512;
                q0 = *(const f32x4*)(nb);
                q1 = *(const f32x4*)(nb + 128);
                q2 = *(const f32x4*)(nb + 256);
                q3 = *(const f32x4*)(nb + 384);
            }
            __syncthreads();
            #pragma unroll
            for (int g = 0; g < 4; ++g) {             // wave's i=64 slice, 4 groups
                int iloc = wid * 64 + g * 16;
                int it = (c * 512 + iloc) >> 4;
                const unsigned short* atp = Atfrag + (size_t)(it * 2) * 512 + lane8;
                bf16x8 a0 = *(const bf16x8*)(atp);
                bf16x8 a1 = *(const bf16x8*)(atp + 512);
                f32x4 d = {0.f, 0.f, 0.f, 0.f};
                d = MFMA16(a0, b0, d);                // lane: delta[o=o0+row][i=base+kq*4+rg]
                d = MFMA16(a1, b1, d);
                f32x4 wv = *(const f32x4*)&stagef[row][iloc + kq * 4];
                #pragma unroll
                for (int rg = 0; rg < 4; ++rg) {
                    float w = wv[rg] + 2.0f * d[rg];
                    nacc[rg] += w * w;
                }
            }
        }
        float ns = nacc[0] + nacc[1] + nacc[2] + nacc[3];
        ns += __shfl_xor(ns, 16, 64);
        ns += __shfl_xor(ns, 32, 64);
        if (kq == 0) part[wid][row] = ns;
        __syncthreads();
        if (tid < 16) {
            float n2 = 0.f;
            #pragma unroll
            for (int w = 0; w < 8; ++w) n2 += part[w][tid];
            mscale[o0 + tid] = mag[o0 + tid] / (sqrtf(n2) + 1e-8f);
        }
    }
}

// ---------------------------------------------------------------------------
// kB: out = (base_output + 2 * xa @ lora_B^T) * mscale
// Two 16m x 256n tiles per block; all fragments coalesced (frag-major).
// ---------------------------------------------------------------------------
__global__ __launch_bounds__(256) void kB(const float* __restrict__ base,
                                          const unsigned short* __restrict__ xafrag,
                                          const unsigned short* __restrict__ Bfrag,
                                          const float* __restrict__ mscale,
                                          float* __restrict__ out) {
    __shared__ float dls[32][260];                   // 33.3 KB, +4 pad
    int tid = threadIdx.x;
    int wid = tid >> 6, lane = tid & 63;
    int row = lane & 15, kq = lane >> 4;
    int m0 = blockIdx.x * 32;
    int n0 = blockIdx.y * 256;
    int col = n0 + lane * 4;
    int lane8 = lane * 8;

    // issue epilogue loads early: they retire under the MFMA phase
    f32x4 bpre[2][4];
    #pragma unroll
    for (int h = 0; h < 2; ++h)
        #pragma unroll
        for (int r = 0; r < 4; ++r)
            bpre[h][r] = __builtin_nontemporal_load(
                (const f32x4*)(base + (size_t)(m0 + h * 16 + wid * 4 + r) * DOUT + col));
    f32x4 msv = *(const f32x4*)(mscale + col);

    // MFMA phase: delta = xa @ B^T for two 16x256 tiles
    bf16x8 xb0[2], xb1[2];
    #pragma unroll
    for (int h = 0; h < 2; ++h) {
        size_t mt = (size_t)(blockIdx.x * 2 + h);
        xb0[h] = *(const bf16x8*)(xafrag + (mt * 2) * 512 + lane8);
        xb1[h] = *(const bf16x8*)(xafrag + (mt * 2 + 1) * 512 + lane8);
    }

    #pragma unroll
    for (int nt = 0; nt < 4; ++nt) {
        size_t ntg = (size_t)((n0 + wid * 64 + nt * 16) >> 4);
        bf16x8 a0 = *(const bf16x8*)(Bfrag + (ntg * 2) * 512 + lane8);
        bf16x8 a1 = *(const bf16x8*)(Bfrag + (ntg * 2 + 1) * 512 + lane8);
        #pragma unroll
        for (int h = 0; h < 2; ++h) {
            f32x4 acc = {0.f, 0.f, 0.f, 0.f};
            acc = MFMA16(a0, xb0[h], acc);           // lane: delta[m=row][nloc=kq*4+rg]
            acc = MFMA16(a1, xb1[h], acc);
            *(f32x4*)&dls[h * 16 + row][wid * 64 + nt * 16 + kq * 4] = acc;
        }
    }
    __syncthreads();

    #pragma unroll
    for (int h = 0; h < 2; ++h)
        #pragma unroll
        for (int r = 0; r < 4; ++r) {
            int m = h * 16 + wid * 4 + r;
            f32x4 d = *(const f32x4*)&dls[m][lane * 4];
            size_t gidx = (size_t)(m0 + m) * DOUT + col;
            f32x4 o;
            #pragma unroll
            for (int j = 0; j < 4; ++j) o[j] = (bpre[h][r][j] + 2.0f * d[j]) * msv[j];
            __builtin_nontemporal_store(o, (f32x4*)(out + gidx));
        }
}

extern "C" void kernel_launch(void* const* d_in, const int* in_sizes, int n_in,
                              void* d_out, int out_size, void* d_ws, size_t ws_size,
                              hipStream_t stream) {
    const float* x    = (const float*)d_in[0];   // [2,4096,4096]
    const float* base = (const float*)d_in[1];   // [2,4096,4096]
    const float* bw   = (const float*)d_in[2];   // [4096,4096]
    const float* lA   = (const float*)d_in[3];   // [64,4096]
    const float* lB   = (const float*)d_in[4];   // [4096,64]
    const float* mag  = (const float*)d_in[5];   // [4096]
    float* out = (float*)d_out;

    char* ws = (char*)d_ws;
    unsigned short* Afrag  = (unsigned short*)(ws);                  // 512 KB
    unsigned short* Atfrag = (unsigned short*)(ws + (512u << 10));   // 512 KB
    unsigned short* Bfrag  = (unsigned short*)(ws + (1024u << 10));  // 512 KB
    unsigned short* xafrag = (unsigned short*)(ws + (1536u << 10));  // 1 MB
    float*          msc    = (float*)(ws + (2560u << 10));           // 16 KB

    hipLaunchKernelGGL(k_prep, dim3(1024), dim3(256), 0, stream, lA, lB, Afrag, Atfrag, Bfrag);
    hipLaunchKernelGGL(kA, dim3(512 + 256), dim3(512), 0, stream,
                       x, Afrag, xafrag, bw, Bfrag, Atfrag, mag, msc);
    hipLaunchKernelGGL(kB, dim3(M_TOT / 32, DOUT / 256), dim3(256), 0, stream,
                       base, xafrag, Bfrag, msc, out);
}